// Round 10
// baseline (277.914 us; speedup 1.0000x reference)
//
#include <hip/hip_runtime.h>
#include <hip/hip_bf16.h>
#include <math.h>

#define TN 201
#define NSTEP 200
#define BATCH 4096
#define DIM 20
#define HID 128

typedef __attribute__((ext_vector_type(8))) short short8;
typedef __attribute__((ext_vector_type(4))) float f32x4;

union S8U { short8 s; unsigned u[4]; };

__device__ __forceinline__ unsigned pk2(float lo, float hi) {
  __hip_bfloat162 h = __float22bfloat162_rn(make_float2(lo, hi));
  union { __hip_bfloat162 h; unsigned u; } v;
  v.h = h;
  return v.u;
}
__device__ __forceinline__ float tanh_fast(float x) {
  float e = __builtin_amdgcn_exp2f(x * 2.8853900817779268f);
  return 1.f - 2.f * __builtin_amdgcn_rcpf(e + 1.f);
}

// ws layout (floats):
//   [0..399]       Pp  = sigma^T P
//   [400..799]     Mp  = -sigma^T A sigma^{-T}
//   [800..1199]    Qp  = sigma^T Q
//   [1200..1399]   dt[200]
//   [1400..1599]   1/sqrt(dt)[200]
//   [1600..1631]   b2p = sigma^T b2 (padded to 32)
//   [2048..4607]   W2p = W2 sigma  [128][20]
//   [5120..7167]   W1F table: 8 frags x 64 lanes x 4 dw   (K: 0..19=x, 20=t)
//   [7168..9215]   W2F table: 8 frags x 64 lanes x 4 dw
//   [9216..9727]   PpF table: 2 frags (K: 0..19 -> Pp[n][k], 20..=0)
//   [9728..10239]  MpF table: 2 frags (K: 0..19 -> Mp[n][k], 20..=0)
//   [10240..10751] B1  table: [nt 0..7][lane 0..63]
//   [12288 ...]    zc: A1[nch][81920], A2[nch][81920], S[nch][81920]

// ================= k0: setup =================
__global__ __launch_bounds__(256) void k0_setup(
    const float* __restrict__ ts, const float* __restrict__ sigma,
    const float* __restrict__ A, const float* __restrict__ P,
    const float* __restrict__ Q, const float* __restrict__ W2,
    const float* __restrict__ b2, const float* __restrict__ W1,
    const float* __restrict__ b1, float* __restrict__ wsc) {
  __shared__ float aug[20][40];
  __shared__ float sS[400], sA[400], sT1[400];
  __shared__ float fac[20];
  int tid = threadIdx.x;
  for (int e = tid; e < 400; e += 256) { sS[e] = sigma[e]; sA[e] = A[e]; }
  for (int e = tid; e < 800; e += 256) {
    int i = e / 40, j = e % 40;
    aug[i][j] = (j < 20) ? sigma[i * 20 + j] : ((j - 20) == i ? 1.f : 0.f);
  }
  __syncthreads();
  for (int p = 0; p < 20; ++p) {
    if (tid < 64) {
      float pv = aug[p][p];
      float r = 1.f / pv;
      float rowv = 0.f, facv = 0.f;
      if (tid < 40) rowv = aug[p][tid];
      if (tid >= 40 && tid < 60) facv = aug[tid - 40][p];
      if (tid < 40) aug[p][tid] = rowv * r;
      if (tid >= 40 && tid < 60) fac[tid - 40] = facv;
    }
    __syncthreads();
    for (int e = tid; e < 800; e += 256) {
      int i = e / 40, j = e % 40;
      if (i != p) aug[i][j] -= fac[i] * aug[p][j];
    }
    __syncthreads();
  }
  // T1[k][j] = (A sigma^{-T})[k][j]
  for (int e = tid; e < 400; e += 256) {
    int k = e / 20, j = e % 20;
    float s = 0.f;
    for (int l2 = 0; l2 < 20; ++l2) s += sA[k * 20 + l2] * aug[j][20 + l2];
    sT1[e] = s;
  }
  __syncthreads();
  for (int e = tid; e < 400; e += 256) {
    int i = e / 20, j = e % 20;
    float m = 0.f, pp = 0.f, qq = 0.f;
    for (int k = 0; k < 20; ++k) {
      float sk = sS[k * 20 + i];
      m += sk * sT1[k * 20 + j];
      pp += sk * P[k * 20 + j];
      qq += sk * Q[k * 20 + j];
    }
    wsc[e] = pp;
    wsc[400 + e] = -m;
    wsc[800 + e] = qq;
  }
  for (int e = tid; e < 2560; e += 256) {
    int h = e / 20, i = e % 20;
    float s = 0.f;
    for (int j = 0; j < 20; ++j) s += W2[h * 20 + j] * sS[j * 20 + i];
    wsc[2048 + e] = s;
  }
  if (tid < 32) {
    float s = 0.f;
    if (tid < 20)
      for (int j = 0; j < 20; ++j) s += b2[j] * sS[j * 20 + tid];
    wsc[1600 + tid] = s;
  }
  if (tid < NSTEP) {
    float d = ts[tid + 1] - ts[tid];
    wsc[1200 + tid] = d;
    wsc[1400 + tid] = rsqrtf(d);
  }
  __syncthreads();

  // ---- prepacked per-lane fragment tables ----
  // K ORDER: cols 0..19 = x0..x19, col 20 = t, rest 0 (aligned float4 loads).
  unsigned* wu = (unsigned*)wsc;
  // W1F: k<20 -> W1 row k+1 (x_k); k==20 -> W1 row 0 (t); else 0
  for (int e = tid; e < 2048; e += 256) {
    int nt = e >> 8, rem = e & 255, l = rem >> 2, jj = rem & 3;
    int quad = l >> 4, m16 = l & 15;
    int n = nt * 16 + m16;
    int k0 = quad * 8 + 2 * jj;
    float f0 = (k0 < 20) ? W1[(k0 + 1) * HID + n] : ((k0 == 20) ? W1[n] : 0.f);
    float f1 = (k0 + 1 < 20) ? W1[(k0 + 2) * HID + n]
                             : ((k0 + 1 == 20) ? W1[n] : 0.f);
    wu[5120 + e] = pk2(f0, f1);
  }
  // W2F
  for (int e = tid; e < 2048; e += 256) {
    int pnt = e >> 8, rem = e & 255, l = rem >> 2, jj = rem & 3;
    int p = pnt >> 1, nt2 = pnt & 1;
    int quad = l >> 4, m16 = l & 15;
    int n = nt2 * 16 + m16;
    bool ok = (n < 20);
    int k0 = p * 32 + quad * 8 + 2 * jj;
    float f0 = ok ? wsc[2048 + k0 * 20 + n] : 0.f;
    float f1 = ok ? wsc[2048 + (k0 + 1) * 20 + n] : 0.f;
    wu[7168 + e] = pk2(f0, f1);
  }
  // PpF: B[k][n] = (k<20) ? Pp[n][k] : 0
  for (int e = tid; e < 512; e += 256) {
    int nt2 = e >> 8, rem = e & 255, l = rem >> 2, jj = rem & 3;
    int quad = l >> 4, m16 = l & 15;
    int n = nt2 * 16 + m16;
    bool ok = (n < 20);
    int k0 = quad * 8 + 2 * jj;
    float f0 = (ok && k0 < 20) ? wsc[n * 20 + k0] : 0.f;
    float f1 = (ok && k0 + 1 < 20) ? wsc[n * 20 + k0 + 1] : 0.f;
    wu[9216 + e] = pk2(f0, f1);
  }
  // MpF: B[k][n] = (k<20) ? Mp[n][k] : 0
  for (int e = tid; e < 512; e += 256) {
    int nt2 = e >> 8, rem = e & 255, l = rem >> 2, jj = rem & 3;
    int quad = l >> 4, m16 = l & 15;
    int n = nt2 * 16 + m16;
    bool ok = (n < 20);
    int k0 = quad * 8 + 2 * jj;
    float f0 = (ok && k0 < 20) ? wsc[400 + n * 20 + k0] : 0.f;
    float f1 = (ok && k0 + 1 < 20) ? wsc[400 + n * 20 + k0 + 1] : 0.f;
    wu[9728 + e] = pk2(f0, f1);
  }
  // B1
  for (int e = tid; e < 512; e += 256) {
    wsc[10240 + e] = b1[(e >> 6) * 16 + (e & 15)];
  }
}

// ================= kernel A: 2-step-interleaved scan =================
// WHY: r7/r8/r9 proved occupancy (27->39%) does NOT move kA (~90us) -- the
// limiter is the per-step serial chain (MFMA->tanh->ds_write->ds_read->MFMA
// x4 + integrand). This version processes TWO t-steps per iteration as
// independent chains (separate H buffers, shared weight frags) interleaved
// in-source: ~2x ILP per wave at unchanged occupancy. Each LDS weight read
// now feeds 2 MFMAs (halved weight-read traffic/step).
// LDS (bytes): H 4 waves x 2 bufs x 1280B = 10240 @ [0,10240);
// tables @ 10240: W1F 8KB | W2F 8KB | PpF 2KB | MpF 2KB -> total 30720.
// (256,3): 170-reg budget, live ~130 with pair state. DO NOT tighten
// ((256,4)/(256,5) spilled in r1/r4/r6). Canary: FETCH >> 115 MB.
#define MFMA16(a, b, c) __builtin_amdgcn_mfma_f32_16x16x32_bf16((a), (b), (c), 0, 0, 0)

__global__ __launch_bounds__(256, 3) void kA(
    const float* __restrict__ states, const float* __restrict__ noises,
    const float* __restrict__ controls, const float* __restrict__ ts,
    const float* __restrict__ wsc, float* __restrict__ zc,
    int nch, int cbase, int crem) {
  __shared__ __align__(16) unsigned char smem[30720];
  __hip_bfloat16* bb = (__hip_bfloat16*)smem;
  const int tid = threadIdx.x;
  const int l = tid & 63;
  const int w = tid >> 6;
  const int quad = l >> 4;
  const int m16 = l & 15;

  const int c = blockIdx.x >> 6;
  const int slab = blockIdx.x & 63;
  const int b0 = slab * 64 + w * 16;
  const int sz = cbase + ((c < crem) ? 1 : 0);
  const int thi = 200 - (c * cbase + ((c < crem) ? c : crem));
  const int tlo = thi - (sz - 1);

  // ---- stage weight tables to LDS (20 KB, coalesced) ----
  {
    const float4* src = (const float4*)(wsc + 5120);
    float4* dst = (float4*)(smem + 10240);
    for (int e = tid; e < 1280; e += 256) dst[e] = src[e];
  }

  float b1v[8];
#pragma unroll
  for (int nt = 0; nt < 8; ++nt) b1v[nt] = wsc[10240 + nt * 64 + l];
  const float b2pv0 = wsc[1600 + m16];
  const float b2pv1 = wsc[1616 + m16];

  // ---- addresses (bf16 units) ----
  const int hU = w * 1280;                 // per-wave H area (2 x 640-unit bufs)
  const int wrH0 = hU + quad * 160 + m16;  // buffer A; buffer B = +640
  const int rdH0 = hU + m16 * 40 + quad * 8;
  const int w1l = 5120 + l * 8;            // W1F per-lane base
  const int w2l = 9216 + l * 8;            // W2F
  const int ppl = 13312 + l * 8;           // PpF
  const int mpl = 14336 + l * 8;           // MpF

  const int row20 = (b0 + m16) * 20;
  const int qoff = (quad == 0) ? 0 : ((quad == 1) ? 8 : 12);
  const float* gx = states + row20 + qoff;
  const float* gn = noises + row20 + qoff;
  const float* gc = controls + row20 + qoff;

  // ---- scan accumulators ----
  f32x4 A1a = {0.f, 0.f, 0.f, 0.f}, A1b = {0.f, 0.f, 0.f, 0.f};
  f32x4 A2a = {0.f, 0.f, 0.f, 0.f}, A2b = {0.f, 0.f, 0.f, 0.f};
  f32x4 La = {0.f, 0.f, 0.f, 0.f}, Lb = {0.f, 0.f, 0.f, 0.f};

  auto bc4 = [](float v) { f32x4 r = {v, v, v, v}; return r; };
  auto pack_af = [&](float4 v0, float4 v1, float tval) -> short8 {
    S8U af;
    if (quad <= 1) {
      af.u[0] = pk2(v0.x, v0.y); af.u[1] = pk2(v0.z, v0.w);
      af.u[2] = pk2(v1.x, v1.y); af.u[3] = pk2(v1.z, v1.w);
    } else if (quad == 2) {
      af.u[0] = pk2(v1.x, v1.y); af.u[1] = pk2(v1.z, v1.w);
      af.u[2] = pk2(tval, 0.f); af.u[3] = 0u;
    } else {
      af.u[0] = af.u[1] = af.u[2] = af.u[3] = 0u;
    }
    return af.s;
  };
  auto pack_yf = [&](float4 n0, float4 n1, float4 c0, float4 c1,
                     float rs) -> short8 {
    S8U yf;
    if (quad <= 1) {
      yf.u[0] = pk2(fmaf(n0.x, rs, c0.x), fmaf(n0.y, rs, c0.y));
      yf.u[1] = pk2(fmaf(n0.z, rs, c0.z), fmaf(n0.w, rs, c0.w));
      yf.u[2] = pk2(fmaf(n1.x, rs, c1.x), fmaf(n1.y, rs, c1.y));
      yf.u[3] = pk2(fmaf(n1.z, rs, c1.z), fmaf(n1.w, rs, c1.w));
    } else if (quad == 2) {
      yf.u[0] = pk2(fmaf(n1.x, rs, c1.x), fmaf(n1.y, rs, c1.y));
      yf.u[1] = pk2(fmaf(n1.z, rs, c1.z), fmaf(n1.w, rs, c1.w));
      yf.u[2] = 0u; yf.u[3] = 0u;
    } else {
      yf.u[0] = yf.u[1] = yf.u[2] = yf.u[3] = 0u;
    }
    return yf.s;
  };
  auto scan_upd = [&](f32x4 u0, f32x4 u1, f32x4 s0, f32x4 s1) {
    La += s0; Lb += s1;
    f32x4 p0 = u0 - La, p1 = u1 - Lb;
    A2a += p0; A2b += p1;
    A1a += p0 * p0; A1b += p1 * p1;
  };

  __syncthreads();  // weight tables visible

  int t = thi;
  int rem = sz;

  // single step (<=2 per chunk: t=200 and/or parity fix); uses H buffer A
  auto do_single = [&](int tt) {
    const bool has_s = (tt < 200);
    size_t rb = (size_t)tt * (BATCH * 20);
    float4 x0 = *(const float4*)(gx + rb), x1 = *(const float4*)(gx + rb + 4);
    float4 n0 = {0,0,0,0}, n1 = {0,0,0,0}, c0 = {0,0,0,0}, c1 = {0,0,0,0};
    if (has_s) {
      n0 = *(const float4*)(gn + rb); n1 = *(const float4*)(gn + rb + 4);
      c0 = *(const float4*)(gc + rb); c1 = *(const float4*)(gc + rb + 4);
    }
    const float tv = ts[tt];
    const float dtv = has_s ? wsc[1200 + tt] : 0.f;
    const float rs = has_s ? wsc[1400 + tt] : 0.f;
    const short8 afs = pack_af(x0, x1, tv);
    f32x4 u0 = bc4(b2pv0), u1 = bc4(b2pv1);
#pragma unroll
    for (int p = 0; p < 4; ++p) {
      short8 w1a = *(const short8*)&bb[w1l + (2 * p) * 512];
      short8 w1b = *(const short8*)&bb[w1l + (2 * p + 1) * 512];
      f32x4 h0 = bc4(b1v[2 * p]);     h0 = MFMA16(afs, w1a, h0);
      f32x4 h1 = bc4(b1v[2 * p + 1]); h1 = MFMA16(afs, w1b, h1);
#pragma unroll
      for (int r = 0; r < 4; ++r) {
        bb[wrH0 + r * 40] = __float2bfloat16(tanh_fast(h0[r]));
        bb[wrH0 + r * 40 + 16] = __float2bfloat16(tanh_fast(h1[r]));
      }
      short8 hf = *(const short8*)&bb[rdH0];
      u0 = MFMA16(hf, *(const short8*)&bb[w2l + (2 * p) * 512], u0);
      u1 = MFMA16(hf, *(const short8*)&bb[w2l + (2 * p + 1) * 512], u1);
    }
    f32x4 s0 = bc4(0.f), s1 = bc4(0.f);
    if (has_s) {
      short8 yfs = pack_yf(n0, n1, c0, c1, rs);
      f32x4 a0 = bc4(0.f), a1 = bc4(0.f);
      a0 = MFMA16(afs, *(const short8*)&bb[ppl], a0);
      a0 = MFMA16(yfs, *(const short8*)&bb[mpl], a0);
      a1 = MFMA16(afs, *(const short8*)&bb[ppl + 512], a1);
      a1 = MFMA16(yfs, *(const short8*)&bb[mpl + 512], a1);
      s0 = a0 * dtv; s1 = a1 * dtv;
    }
    scan_upd(u0, u1, s0, s1);
  };

  if (t == 200) { do_single(t); --t; --rem; }
  if (rem & 1) { do_single(t); --t; --rem; }

  if (rem > 0) {
    // preload x for first pair (A=t, B=t-1); all pairs have has_s
    float4 xa0, xa1, xb0, xb1;
    {
      size_t rbA = (size_t)t * (BATCH * 20);
      size_t rbB = rbA - (size_t)(BATCH * 20);
      xa0 = *(const float4*)(gx + rbA); xa1 = *(const float4*)(gx + rbA + 4);
      xb0 = *(const float4*)(gx + rbB); xb1 = *(const float4*)(gx + rbB + 4);
    }
#pragma unroll 1
    for (; t >= tlo + 1; t -= 2) {
      size_t rbA = (size_t)t * (BATCH * 20);
      size_t rbB = rbA - (size_t)(BATCH * 20);
      // n/c for this pair (needed only mid-body -> latency hidden by MLP)
      float4 na0 = *(const float4*)(gn + rbA), na1 = *(const float4*)(gn + rbA + 4);
      float4 ca0 = *(const float4*)(gc + rbA), ca1 = *(const float4*)(gc + rbA + 4);
      float4 nb0 = *(const float4*)(gn + rbB), nb1 = *(const float4*)(gn + rbB + 4);
      float4 cb0 = *(const float4*)(gc + rbB), cb1 = *(const float4*)(gc + rbB + 4);
      // x prefetch for next pair
      const bool more = (t - 2 >= tlo + 1);
      float4 xpa0, xpa1, xpb0, xpb1;
      if (more) {
        size_t rb2 = rbB - (size_t)(BATCH * 20);
        size_t rb3 = rb2 - (size_t)(BATCH * 20);
        xpa0 = *(const float4*)(gx + rb2); xpa1 = *(const float4*)(gx + rb2 + 4);
        xpb0 = *(const float4*)(gx + rb3); xpb1 = *(const float4*)(gx + rb3 + 4);
      }
      const float tvA = ts[t], tvB = ts[t - 1];
      const float dtA = wsc[1200 + t], dtB = wsc[1200 + t - 1];
      const float rsA = wsc[1400 + t], rsB = wsc[1400 + t - 1];

      const short8 afA = pack_af(xa0, xa1, tvA);
      const short8 afB = pack_af(xb0, xb1, tvB);

      // ---- interleaved dual-MLP: chains A and B share weight frags ----
      f32x4 u0A = bc4(b2pv0), u1A = bc4(b2pv1);
      f32x4 u0B = bc4(b2pv0), u1B = bc4(b2pv1);
#pragma unroll
      for (int p = 0; p < 4; ++p) {
        short8 w1a = *(const short8*)&bb[w1l + (2 * p) * 512];
        short8 w1b = *(const short8*)&bb[w1l + (2 * p + 1) * 512];
        f32x4 hA0 = bc4(b1v[2 * p]);     hA0 = MFMA16(afA, w1a, hA0);
        f32x4 hA1 = bc4(b1v[2 * p + 1]); hA1 = MFMA16(afA, w1b, hA1);
        f32x4 hB0 = bc4(b1v[2 * p]);     hB0 = MFMA16(afB, w1a, hB0);
        f32x4 hB1 = bc4(b1v[2 * p + 1]); hB1 = MFMA16(afB, w1b, hB1);
#pragma unroll
        for (int r = 0; r < 4; ++r) {
          bb[wrH0 + r * 40] = __float2bfloat16(tanh_fast(hA0[r]));
          bb[wrH0 + r * 40 + 16] = __float2bfloat16(tanh_fast(hA1[r]));
          bb[wrH0 + 640 + r * 40] = __float2bfloat16(tanh_fast(hB0[r]));
          bb[wrH0 + 640 + r * 40 + 16] = __float2bfloat16(tanh_fast(hB1[r]));
        }
        short8 hfA = *(const short8*)&bb[rdH0];
        short8 hfB = *(const short8*)&bb[rdH0 + 640];
        short8 w2a = *(const short8*)&bb[w2l + (2 * p) * 512];
        short8 w2b = *(const short8*)&bb[w2l + (2 * p + 1) * 512];
        u0A = MFMA16(hfA, w2a, u0A); u1A = MFMA16(hfA, w2b, u1A);
        u0B = MFMA16(hfB, w2a, u0B); u1B = MFMA16(hfB, w2b, u1B);
      }

      // ---- dual integrand ----
      const short8 yfA = pack_yf(na0, na1, ca0, ca1, rsA);
      const short8 yfB = pack_yf(nb0, nb1, cb0, cb1, rsB);
      short8 pp0 = *(const short8*)&bb[ppl];
      short8 pp1 = *(const short8*)&bb[ppl + 512];
      short8 mp0 = *(const short8*)&bb[mpl];
      short8 mp1 = *(const short8*)&bb[mpl + 512];
      f32x4 a0A = bc4(0.f); a0A = MFMA16(afA, pp0, a0A); a0A = MFMA16(yfA, mp0, a0A);
      f32x4 a1A = bc4(0.f); a1A = MFMA16(afA, pp1, a1A); a1A = MFMA16(yfA, mp1, a1A);
      f32x4 a0B = bc4(0.f); a0B = MFMA16(afB, pp0, a0B); a0B = MFMA16(yfB, mp0, a0B);
      f32x4 a1B = bc4(0.f); a1B = MFMA16(afB, pp1, a1B); a1B = MFMA16(yfB, mp1, a1B);

      // ---- ordered scan: A (=t) first, then B (=t-1) ----
      scan_upd(u0A, u1A, a0A * dtA, a1A * dtA);
      scan_upd(u0B, u1B, a0B * dtB, a1B * dtB);

      if (more) { xa0 = xpa0; xa1 = xpa1; xb0 = xpb0; xb1 = xpb1; }
    }
  }

  // ---- epilogue stores ----
  const size_t CH = (size_t)BATCH * DIM;
  float* zA1 = zc;
  float* zA2 = zc + (size_t)nch * CH;
  float* zS = zc + (size_t)2 * nch * CH;
  const int bb2 = b0 + quad * 4;
#pragma unroll
  for (int reg = 0; reg < 4; ++reg) {
    size_t base = ((size_t)c * BATCH + (bb2 + reg)) * 20;
    zA1[base + m16] = A1a[reg];
    zA2[base + m16] = A2a[reg];
    zS[base + m16] = La[reg];
    if (m16 < 4) {
      zA1[base + 16 + m16] = A1b[reg];
      zA2[base + 16 + m16] = A2b[reg];
      zS[base + 16 + m16] = Lb[reg];
    }
  }
}

// ================= kernel B: combine chunks =================
__global__ __launch_bounds__(256) void kB(
    const float* __restrict__ states, const float* __restrict__ lw,
    const float* __restrict__ wsc, const float* __restrict__ zc,
    float* __restrict__ out, int nch, int cbase, int crem) {
  __shared__ float sQp[400];
  __shared__ float part[4];
  int tid = threadIdx.x;
  for (int e = tid; e < 400; e += 256) sQp[e] = wsc[800 + e];
  __syncthreads();
  const int u = blockIdx.x * 256 + tid;
  const int b = u / 20;
  const int i = u - b * 20;
  const float* xp = states + ((size_t)NSTEP * BATCH + b) * 20;
  float term = 0.f;
#pragma unroll
  for (int j = 0; j < 20; ++j) term = fmaf(sQp[i * 20 + j], xp[j], term);

  const size_t CH = (size_t)BATCH * DIM;
  float T = 0.f, obj = 0.f;
  for (int c = 0; c < nch; ++c) {
    float A1 = zc[(size_t)c * CH + u];
    float A2 = zc[(size_t)(nch + c) * CH + u];
    float S = zc[(size_t)(2 * nch + c) * CH + u];
    float K = term + T;
    float nc = (float)(cbase + ((c < crem) ? 1 : 0));
    obj += A1 - 2.f * K * A2 + nc * K * K;
    T += S;
  }
  obj *= __expf(lw[b]) * (1.f / ((float)TN * (float)BATCH));
#pragma unroll
  for (int off = 32; off > 0; off >>= 1) obj += __shfl_down(obj, off, 64);
  if ((tid & 63) == 0) part[tid >> 6] = obj;
  __syncthreads();
  if (tid == 0) atomicAdd(out, (part[0] + part[1]) + (part[2] + part[3]));
}

extern "C" void kernel_launch(void* const* d_in, const int* in_sizes, int n_in,
                              void* d_out, int out_size, void* d_ws, size_t ws_size,
                              hipStream_t stream) {
  const float* states = (const float*)d_in[0];
  const float* noises = (const float*)d_in[1];
  const float* controls = (const float*)d_in[2];
  const float* lw = (const float*)d_in[3];
  const float* ts = (const float*)d_in[4];
  const float* sigma = (const float*)d_in[5];
  const float* P = (const float*)d_in[6];
  const float* A = (const float*)d_in[7];
  const float* Q = (const float*)d_in[8];
  const float* W1 = (const float*)d_in[9];
  const float* b1 = (const float*)d_in[10];
  const float* W2 = (const float*)d_in[11];
  const float* b2 = (const float*)d_in[12];
  float* out = (float*)d_out;

  float* wsc = (float*)d_ws;
  float* zc = wsc + 12288;

  // nch=12 -> 768 blocks = 3 blocks/CU (occupancy is NOT the lever, r7-r9;
  // ILP per wave is). Fallback 8 for small workspaces.
  int nch = 12;
  size_t need = ((size_t)12288 + (size_t)3 * nch * BATCH * DIM) * sizeof(float);
  if (ws_size < need) nch = 8;
  int cbase = TN / nch;
  int crem = TN - cbase * nch;

  hipMemsetAsync(out, 0, sizeof(float), stream);
  hipLaunchKernelGGL(k0_setup, dim3(1), dim3(256), 0, stream,
                     ts, sigma, A, P, Q, W2, b2, W1, b1, wsc);
  hipLaunchKernelGGL(kA, dim3(nch * 64), dim3(256), 0, stream,
                     states, noises, controls, ts, wsc, zc, nch, cbase, crem);
  hipLaunchKernelGGL(kB, dim3((BATCH * DIM) / 256), dim3(256), 0, stream,
                     states, lw, wsc, zc, out, nch, cbase, crem);
}

// Round 12
// 271.357 us; speedup vs baseline: 1.0242x; 1.0242x over previous
//
#include <hip/hip_runtime.h>
#include <hip/hip_bf16.h>
#include <math.h>

#define TN 201
#define NSTEP 200
#define BATCH 4096
#define DIM 20
#define HID 128

typedef __attribute__((ext_vector_type(8))) short short8;
typedef __attribute__((ext_vector_type(4))) short sv4;  // NOT "short4": HIP defines that type
typedef __attribute__((ext_vector_type(4))) float f32x4;

union S8U { short8 s; unsigned u[4]; };
union S4U { sv4 s; unsigned u[2]; };

__device__ __forceinline__ unsigned pk2(float lo, float hi) {
  __hip_bfloat162 h = __float22bfloat162_rn(make_float2(lo, hi));
  union { __hip_bfloat162 h; unsigned u; } v;
  v.h = h;
  return v.u;
}
__device__ __forceinline__ float tanh_fast(float x) {
  float e = __builtin_amdgcn_exp2f(x * 2.8853900817779268f);
  return 1.f - 2.f * __builtin_amdgcn_rcpf(e + 1.f);
}

#define MFMA32(a, b, c) __builtin_amdgcn_mfma_f32_16x16x32_bf16((a), (b), (c), 0, 0, 0)

// 16x16x16 bf16 MFMA (A/B = 4 bf16 = 2 VGPRs). Prefer the builtin; fall back
// to inline asm (v_mfma_f32_16x16x16_bf16 exists on gfx950 per ISA 10).
#if defined(__has_builtin)
#if __has_builtin(__builtin_amdgcn_mfma_f32_16x16x16bf16_1k)
#define MFMA16K(a, b, c) __builtin_amdgcn_mfma_f32_16x16x16bf16_1k((a), (b), (c), 0, 0, 0)
#endif
#endif
#ifndef MFMA16K
__device__ __forceinline__ f32x4 mfma16k_asm(sv4 a, sv4 b, f32x4 c) {
  f32x4 d;
  asm volatile("v_mfma_f32_16x16x16_bf16 %0, %1, %2, %3"
               : "=v"(d) : "v"(a), "v"(b), "v"(c));
  return d;
}
#define MFMA16K(a, b, c) mfma16k_asm((a), (b), (c))
#endif

// ws layout (floats):
//   [0..399]       Pp  = sigma^T P        (Pp[d][k])
//   [400..799]     Mp  = -sigma^T A sigma^{-T}
//   [800..1199]    Qp  = sigma^T Q
//   [1200..1399]   dt[200]
//   [1400..1599]   1/sqrt(dt)[200]
//   [1600..1631]   b2p = sigma^T b2 (padded to 32, zeros beyond 20)
//   [2048..4607]   W2p = W2 sigma  [128][20]
//   [5120..7167]   W1TF: 8 frags x 64 lanes x 4 dw  (A-frag, layer1^T;
//                        A[n][k]: k<20 -> W1[k+1][n], k==20 -> W1[0][n] (t),
//                        k==21 -> b1[n] (bias col), else 0)
//   [7168..9215]   W2PTF: 16 frags (hk*2+tile) x 64 lanes x 2 dw (A-frag,
//                        layer2^T 16x16x16; A[d][h']=W2p[hk*16+h'][d])
//   [9216..9727]   PPTF: 2 tiles x 64 x 4 dw (A-frag; A[d][k]=Pp[d][k])
//   [9728..10239]  MPTF: 2 tiles x 64 x 4 dw (A[d][k]=Mp[d][k])
//   [12288 ...]    zc: A1[nch][81920], A2[nch][81920], S[nch][81920]

// ================= k0: setup =================
__global__ __launch_bounds__(256) void k0_setup(
    const float* __restrict__ ts, const float* __restrict__ sigma,
    const float* __restrict__ A, const float* __restrict__ P,
    const float* __restrict__ Q, const float* __restrict__ W2,
    const float* __restrict__ b2, const float* __restrict__ W1,
    const float* __restrict__ b1, float* __restrict__ wsc) {
  __shared__ float aug[20][40];
  __shared__ float sS[400], sA[400], sT1[400];
  __shared__ float fac[20];
  int tid = threadIdx.x;
  for (int e = tid; e < 400; e += 256) { sS[e] = sigma[e]; sA[e] = A[e]; }
  for (int e = tid; e < 800; e += 256) {
    int i = e / 40, j = e % 40;
    aug[i][j] = (j < 20) ? sigma[i * 20 + j] : ((j - 20) == i ? 1.f : 0.f);
  }
  __syncthreads();
  for (int p = 0; p < 20; ++p) {
    if (tid < 64) {
      float pv = aug[p][p];
      float r = 1.f / pv;
      float rowv = 0.f, facv = 0.f;
      if (tid < 40) rowv = aug[p][tid];
      if (tid >= 40 && tid < 60) facv = aug[tid - 40][p];
      if (tid < 40) aug[p][tid] = rowv * r;
      if (tid >= 40 && tid < 60) fac[tid - 40] = facv;
    }
    __syncthreads();
    for (int e = tid; e < 800; e += 256) {
      int i = e / 40, j = e % 40;
      if (i != p) aug[i][j] -= fac[i] * aug[p][j];
    }
    __syncthreads();
  }
  // T1[k][j] = (A sigma^{-T})[k][j]
  for (int e = tid; e < 400; e += 256) {
    int k = e / 20, j = e % 20;
    float s = 0.f;
    for (int l2 = 0; l2 < 20; ++l2) s += sA[k * 20 + l2] * aug[j][20 + l2];
    sT1[e] = s;
  }
  __syncthreads();
  for (int e = tid; e < 400; e += 256) {
    int i = e / 20, j = e % 20;
    float m = 0.f, pp = 0.f, qq = 0.f;
    for (int k = 0; k < 20; ++k) {
      float sk = sS[k * 20 + i];
      m += sk * sT1[k * 20 + j];
      pp += sk * P[k * 20 + j];
      qq += sk * Q[k * 20 + j];
    }
    wsc[e] = pp;
    wsc[400 + e] = -m;
    wsc[800 + e] = qq;
  }
  for (int e = tid; e < 2560; e += 256) {
    int h = e / 20, i = e % 20;
    float s = 0.f;
    for (int j = 0; j < 20; ++j) s += W2[h * 20 + j] * sS[j * 20 + i];
    wsc[2048 + e] = s;
  }
  if (tid < 32) {
    float s = 0.f;
    if (tid < 20)
      for (int j = 0; j < 20; ++j) s += b2[j] * sS[j * 20 + tid];
    wsc[1600 + tid] = s;
  }
  if (tid < NSTEP) {
    float d = ts[tid + 1] - ts[tid];
    wsc[1200 + tid] = d;
    wsc[1400 + tid] = rsqrtf(d);
  }
  __syncthreads();

  unsigned* wu = (unsigned*)wsc;
  // W1TF (layer1^T A-frag): lane(quad,m16), n = nt*16+m16, k = quad*8+j
  for (int e = tid; e < 2048; e += 256) {
    int nt = e >> 8, rem = e & 255, l = rem >> 2, jj = rem & 3;
    int quad = l >> 4, m16 = l & 15;
    int n = nt * 16 + m16;
    int k0 = quad * 8 + 2 * jj;
    auto wf = [&](int k) -> float {
      if (k < 20) return W1[(k + 1) * HID + n];
      if (k == 20) return W1[n];       // t row
      if (k == 21) return b1[n];       // bias column (X supplies 1.0)
      return 0.f;
    };
    wu[5120 + e] = pk2(wf(k0), wf(k0 + 1));
  }
  // W2PTF (layer2^T 16x16x16 A-frags): frag f = hk*2+tile; 2 dw/lane
  for (int e = tid; e < 2048; e += 256) {
    int f = e >> 7, rem = e & 127, l = rem >> 1, jj = rem & 1;
    int hk = f >> 1, tile = f & 1;
    int m16 = l & 15;
    int quad = l >> 4;
    int d = tile ? 16 + m16 : m16;
    bool ok = (d < 20);
    int h0 = hk * 16 + quad * 4 + 2 * jj;
    float f0 = ok ? wsc[2048 + h0 * 20 + d] : 0.f;
    float f1 = ok ? wsc[2048 + (h0 + 1) * 20 + d] : 0.f;
    wu[7168 + e] = pk2(f0, f1);
  }
  // PPTF / MPTF (integrand^T A-frags, K=32 layout): tile in {0,1}
  for (int e = tid; e < 512; e += 256) {
    int tile = e >> 8, rem = e & 255, l = rem >> 2, jj = rem & 3;
    int quad = l >> 4, m16 = l & 15;
    int d = tile ? 16 + m16 : m16;
    bool ok = (d < 20);
    int k0 = quad * 8 + 2 * jj;
    float f0 = (ok && k0 < 20) ? wsc[d * 20 + k0] : 0.f;
    float f1 = (ok && k0 + 1 < 20) ? wsc[d * 20 + k0 + 1] : 0.f;
    wu[9216 + e] = pk2(f0, f1);
    float g0 = (ok && k0 < 20) ? wsc[400 + d * 20 + k0] : 0.f;
    float g1 = (ok && k0 + 1 < 20) ? wsc[400 + d * 20 + k0 + 1] : 0.f;
    wu[9728 + e] = pk2(g0, g1);
  }
}

// ================= kernel A: fully-transposed MLP scan, ZERO LDS =================
// Layer1^T: H^T = mfma32(A=W1T, B=X^T). The C output (lane: rows quad*4+reg,
// col m16) is EXACTLY the B-fragment layout of v_mfma_f32_16x16x16_bf16, so
// layer2^T consumes tanh(H) from registers -- no LDS round-trip anywhere.
// Bias b1 folded into K=21 (X supplies 1.0); b2p via C-init; integrand^T
// reuses the X fragment. All weights live in regs (~80; MFMA reads AGPRs).
// (256,2): 256-reg unified budget (r2-proven no-spill at this live-set size).
// Canaries: FETCH >> 100 MB or WRITE >> 20 MB = spill; LDS_Block_Size must be 0.
__global__ __launch_bounds__(256, 2) void kA(
    const float* __restrict__ states, const float* __restrict__ noises,
    const float* __restrict__ controls, const float* __restrict__ ts,
    const float* __restrict__ wsc, float* __restrict__ zc,
    int nch, int cbase, int crem) {
  const int tid = threadIdx.x;
  const int l = tid & 63;
  const int w = tid >> 6;
  const int quad = l >> 4;
  const int m16 = l & 15;

  const int c = blockIdx.x >> 6;
  const int slab = blockIdx.x & 63;
  const int b0 = slab * 64 + w * 16;
  const int sz = cbase + ((c < crem) ? 1 : 0);
  const int thi = 200 - (c * cbase + ((c < crem) ? c : crem));
  const int tlo = thi - (sz - 1);

  // ---- weight fragments (coalesced loads from prepacked tables) ----
  short8 W1T[8];
#pragma unroll
  for (int nt = 0; nt < 8; ++nt)
    W1T[nt] = *(const short8*)(wsc + 5120 + nt * 256 + l * 4);
  sv4 W2T[16];
#pragma unroll
  for (int f = 0; f < 16; ++f)
    W2T[f] = *(const sv4*)(wsc + 7168 + f * 128 + l * 2);
  const short8 PPT0 = *(const short8*)(wsc + 9216 + l * 4);
  const short8 PPT1 = *(const short8*)(wsc + 9472 + l * 4);
  const short8 MPT0 = *(const short8*)(wsc + 9728 + l * 4);
  const short8 MPT1 = *(const short8*)(wsc + 9984 + l * 4);
  const f32x4 b2Av = *(const f32x4*)(wsc + 1600 + quad * 4);
  const f32x4 b2Bv = *(const f32x4*)(wsc + 1616 + quad * 4);

  // ---- global pointers (16B-aligned per-quad slices) ----
  const int row20 = (b0 + m16) * 20;
  const int qoff = (quad == 0) ? 0 : ((quad == 1) ? 8 : 12);
  const float* gx = states + row20 + qoff;
  const float* gn = noises + row20 + qoff;
  const float* gc = controls + row20 + qoff;

  // ---- scan accumulators (tile0: d=quad*4+reg; tile1: d=16+reg, quad0 only) ----
  f32x4 A1a = {0.f, 0.f, 0.f, 0.f}, A1b = {0.f, 0.f, 0.f, 0.f};
  f32x4 A2a = {0.f, 0.f, 0.f, 0.f}, A2b = {0.f, 0.f, 0.f, 0.f};
  f32x4 La = {0.f, 0.f, 0.f, 0.f}, Lb = {0.f, 0.f, 0.f, 0.f};

  // ---- preload first t ----
  float4 xv0, xv1, nv0 = {0, 0, 0, 0}, nv1 = {0, 0, 0, 0};
  float4 cv0 = {0, 0, 0, 0}, cv1 = {0, 0, 0, 0};
  {
    size_t rb = (size_t)thi * (BATCH * 20);
    xv0 = *(const float4*)(gx + rb);
    xv1 = *(const float4*)(gx + rb + 4);
    if (thi < 200) {
      nv0 = *(const float4*)(gn + rb); nv1 = *(const float4*)(gn + rb + 4);
      cv0 = *(const float4*)(gc + rb); cv1 = *(const float4*)(gc + rb + 4);
    }
  }

#pragma unroll 1
  for (int t = thi; t >= tlo; --t) {
    float4 xn0, xn1, nn0, nn1, cn0, cn1;
    if (t > tlo) {
      size_t rb = (size_t)(t - 1) * (BATCH * 20);
      xn0 = *(const float4*)(gx + rb); xn1 = *(const float4*)(gx + rb + 4);
      nn0 = *(const float4*)(gn + rb); nn1 = *(const float4*)(gn + rb + 4);
      cn0 = *(const float4*)(gc + rb); cn1 = *(const float4*)(gc + rb + 4);
    }
    const float tval = ts[t];
    const bool has_s = (t < 200);
    const float dtv = has_s ? wsc[1200 + t] : 0.f;
    const float rsd = has_s ? wsc[1400 + t] : 0.f;

    // ---- X^T B-fragment (K order: x0..x19, t@20, 1.0@21) ----
    S8U af;
    if (quad <= 1) {
      af.u[0] = pk2(xv0.x, xv0.y); af.u[1] = pk2(xv0.z, xv0.w);
      af.u[2] = pk2(xv1.x, xv1.y); af.u[3] = pk2(xv1.z, xv1.w);
    } else if (quad == 2) {        // loads were x[12..19]
      af.u[0] = pk2(xv1.x, xv1.y); af.u[1] = pk2(xv1.z, xv1.w);
      af.u[2] = pk2(tval, 1.0f);   af.u[3] = 0u;
    } else {
      af.u[0] = af.u[1] = af.u[2] = af.u[3] = 0u;
    }
    const short8 afs = af.s;

    const f32x4 z4 = {0.f, 0.f, 0.f, 0.f};
    // ---- layer1^T: 8 independent MFMAs -> lane holds H^T[16nt+quad*4+reg][m16]
    f32x4 h0 = MFMA32(W1T[0], afs, z4);
    f32x4 h1 = MFMA32(W1T[1], afs, z4);
    f32x4 h2 = MFMA32(W1T[2], afs, z4);
    f32x4 h3 = MFMA32(W1T[3], afs, z4);
    f32x4 h4 = MFMA32(W1T[4], afs, z4);
    f32x4 h5 = MFMA32(W1T[5], afs, z4);
    f32x4 h6 = MFMA32(W1T[6], afs, z4);
    f32x4 h7 = MFMA32(W1T[7], afs, z4);

    // ---- layer2^T: tanh in regs -> 16x16x16 MFMAs, no lane permutation ----
    f32x4 u0 = b2Av, u1 = b2Bv;
#define L2STEP(hk, hr)                                                  \
    {                                                                   \
      S4U hb;                                                           \
      hb.u[0] = pk2(tanh_fast(hr[0]), tanh_fast(hr[1]));                \
      hb.u[1] = pk2(tanh_fast(hr[2]), tanh_fast(hr[3]));                \
      u0 = MFMA16K(W2T[2 * hk], hb.s, u0);                              \
      u1 = MFMA16K(W2T[2 * hk + 1], hb.s, u1);                          \
    }
    L2STEP(0, h0) L2STEP(1, h1) L2STEP(2, h2) L2STEP(3, h3)
    L2STEP(4, h4) L2STEP(5, h5) L2STEP(6, h6) L2STEP(7, h7)
#undef L2STEP

    // ---- integrand^T: S^T = Pp.X^T + Mp.Y^T (X frag reused) ----
    f32x4 s0 = z4, s1 = z4;
    if (has_s) {
      S8U yf;
      if (quad <= 1) {
        yf.u[0] = pk2(fmaf(nv0.x, rsd, cv0.x), fmaf(nv0.y, rsd, cv0.y));
        yf.u[1] = pk2(fmaf(nv0.z, rsd, cv0.z), fmaf(nv0.w, rsd, cv0.w));
        yf.u[2] = pk2(fmaf(nv1.x, rsd, cv1.x), fmaf(nv1.y, rsd, cv1.y));
        yf.u[3] = pk2(fmaf(nv1.z, rsd, cv1.z), fmaf(nv1.w, rsd, cv1.w));
      } else if (quad == 2) {
        yf.u[0] = pk2(fmaf(nv1.x, rsd, cv1.x), fmaf(nv1.y, rsd, cv1.y));
        yf.u[1] = pk2(fmaf(nv1.z, rsd, cv1.z), fmaf(nv1.w, rsd, cv1.w));
        yf.u[2] = 0u; yf.u[3] = 0u;
      } else {
        yf.u[0] = yf.u[1] = yf.u[2] = yf.u[3] = 0u;
      }
      f32x4 a0 = MFMA32(PPT0, afs, z4);
      a0 = MFMA32(MPT0, yf.s, a0);
      f32x4 a1 = MFMA32(PPT1, afs, z4);
      a1 = MFMA32(MPT1, yf.s, a1);
      s0 = a0 * dtv;
      s1 = a1 * dtv;
    }

    // ---- scan update ----
    La += s0;
    Lb += s1;
    f32x4 p0 = u0 - La;
    f32x4 p1 = u1 - Lb;
    A2a += p0;
    A2b += p1;
    A1a += p0 * p0;
    A1b += p1 * p1;

    // rotate prefetch
    xv0 = xn0; xv1 = xn1;
    nv0 = nn0; nv1 = nn1;
    cv0 = cn0; cv1 = cn1;
  }

  // ---- epilogue: lane owns batch b0+m16, dims quad*4+reg (+16.. for quad0) ----
  const size_t CH = (size_t)BATCH * DIM;
  float* zA1 = zc;
  float* zA2 = zc + (size_t)nch * CH;
  float* zS = zc + (size_t)2 * nch * CH;
  size_t base = ((size_t)c * BATCH + (b0 + m16)) * 20 + quad * 4;
#pragma unroll
  for (int reg = 0; reg < 4; ++reg) {
    zA1[base + reg] = A1a[reg];
    zA2[base + reg] = A2a[reg];
    zS[base + reg] = La[reg];
  }
  if (quad == 0) {
#pragma unroll
    for (int reg = 0; reg < 4; ++reg) {
      zA1[base + 16 + reg] = A1b[reg];
      zA2[base + 16 + reg] = A2b[reg];
      zS[base + 16 + reg] = Lb[reg];
    }
  }
}

// ================= kernel B: combine chunks =================
__global__ __launch_bounds__(256) void kB(
    const float* __restrict__ states, const float* __restrict__ lw,
    const float* __restrict__ wsc, const float* __restrict__ zc,
    float* __restrict__ out, int nch, int cbase, int crem) {
  __shared__ float sQp[400];
  __shared__ float part[4];
  int tid = threadIdx.x;
  for (int e = tid; e < 400; e += 256) sQp[e] = wsc[800 + e];
  __syncthreads();
  const int u = blockIdx.x * 256 + tid;
  const int b = u / 20;
  const int i = u - b * 20;
  const float* xp = states + ((size_t)NSTEP * BATCH + b) * 20;
  float term = 0.f;
#pragma unroll
  for (int j = 0; j < 20; ++j) term = fmaf(sQp[i * 20 + j], xp[j], term);

  const size_t CH = (size_t)BATCH * DIM;
  float T = 0.f, obj = 0.f;
  for (int c = 0; c < nch; ++c) {
    float A1 = zc[(size_t)c * CH + u];
    float A2 = zc[(size_t)(nch + c) * CH + u];
    float S = zc[(size_t)(2 * nch + c) * CH + u];
    float K = term + T;
    float nc = (float)(cbase + ((c < crem) ? 1 : 0));
    obj += A1 - 2.f * K * A2 + nc * K * K;
    T += S;
  }
  obj *= __expf(lw[b]) * (1.f / ((float)TN * (float)BATCH));
#pragma unroll
  for (int off = 32; off > 0; off >>= 1) obj += __shfl_down(obj, off, 64);
  if ((tid & 63) == 0) part[tid >> 6] = obj;
  __syncthreads();
  if (tid == 0) atomicAdd(out, (part[0] + part[1]) + (part[2] + part[3]));
}

extern "C" void kernel_launch(void* const* d_in, const int* in_sizes, int n_in,
                              void* d_out, int out_size, void* d_ws, size_t ws_size,
                              hipStream_t stream) {
  const float* states = (const float*)d_in[0];
  const float* noises = (const float*)d_in[1];
  const float* controls = (const float*)d_in[2];
  const float* lw = (const float*)d_in[3];
  const float* ts = (const float*)d_in[4];
  const float* sigma = (const float*)d_in[5];
  const float* P = (const float*)d_in[6];
  const float* A = (const float*)d_in[7];
  const float* Q = (const float*)d_in[8];
  const float* W1 = (const float*)d_in[9];
  const float* b1 = (const float*)d_in[10];
  const float* W2 = (const float*)d_in[11];
  const float* b2 = (const float*)d_in[12];
  float* out = (float*)d_out;

  float* wsc = (float*)d_ws;
  float* zc = wsc + 12288;

  // nch=12 -> 768 blocks = 3/CU offered (occupancy is not the lever, r7-r9;
  // short critical path is).
  int nch = 12;
  size_t need = ((size_t)12288 + (size_t)3 * nch * BATCH * DIM) * sizeof(float);
  if (ws_size < need) nch = 8;
  int cbase = TN / nch;
  int crem = TN - cbase * nch;

  (void)hipMemsetAsync(out, 0, sizeof(float), stream);
  hipLaunchKernelGGL(k0_setup, dim3(1), dim3(256), 0, stream,
                     ts, sigma, A, P, Q, W2, b2, W1, b1, wsc);
  hipLaunchKernelGGL(kA, dim3(nch * 64), dim3(256), 0, stream,
                     states, noises, controls, ts, wsc, zc, nch, cbase, crem);
  hipLaunchKernelGGL(kB, dim3((BATCH * DIM) / 256), dim3(256), 0, stream,
                     states, lw, wsc, zc, out, nch, cbase, crem);
}

// Round 13
// 263.253 us; speedup vs baseline: 1.0557x; 1.0308x over previous
//
#include <hip/hip_runtime.h>
#include <hip/hip_bf16.h>
#include <math.h>

#define TN 201
#define NSTEP 200
#define BATCH 4096
#define DIM 20
#define HID 128

typedef __attribute__((ext_vector_type(8))) short short8;
typedef __attribute__((ext_vector_type(4))) short sv4;  // NOT "short4": HIP defines that type
typedef __attribute__((ext_vector_type(4))) float f32x4;

union S8U { short8 s; unsigned u[4]; };
union S4U { sv4 s; unsigned u[2]; };

__device__ __forceinline__ unsigned pk2(float lo, float hi) {
  __hip_bfloat162 h = __float22bfloat162_rn(make_float2(lo, hi));
  union { __hip_bfloat162 h; unsigned u; } v;
  v.h = h;
  return v.u;
}
__device__ __forceinline__ float tanh_fast(float x) {
  float e = __builtin_amdgcn_exp2f(x * 2.8853900817779268f);
  return 1.f - 2.f * __builtin_amdgcn_rcpf(e + 1.f);
}

#define MFMA32(a, b, c) __builtin_amdgcn_mfma_f32_16x16x32_bf16((a), (b), (c), 0, 0, 0)

// 16x16x16 bf16 MFMA (A/B = 4 bf16 = 2 VGPRs).
#if defined(__has_builtin)
#if __has_builtin(__builtin_amdgcn_mfma_f32_16x16x16bf16_1k)
#define MFMA16K(a, b, c) __builtin_amdgcn_mfma_f32_16x16x16bf16_1k((a), (b), (c), 0, 0, 0)
#endif
#endif
#ifndef MFMA16K
__device__ __forceinline__ f32x4 mfma16k_asm(sv4 a, sv4 b, f32x4 c) {
  f32x4 d;
  asm volatile("v_mfma_f32_16x16x16_bf16 %0, %1, %2, %3"
               : "=v"(d) : "v"(a), "v"(b), "v"(c));
  return d;
}
#define MFMA16K(a, b, c) mfma16k_asm((a), (b), (c))
#endif

// ws layout (floats):
//   [0..399]       Pp  = sigma^T P        (Pp[d][k])
//   [400..799]     Mp  = -sigma^T A sigma^{-T}
//   [800..1199]    Qp  = sigma^T Q
//   [1200..1399]   dt[200]
//   [1400..1599]   1/sqrt(dt)[200]
//   [1600..1631]   b2p = sigma^T b2 (padded to 32, zeros beyond 20)
//   [2048..4607]   W2p = W2 sigma  [128][20]
//   [5120..7167]   W1TF: 8 frags x 64 lanes x 4 dw  (A-frag, layer1^T)
//   [7168..9215]   W2PTF: 16 frags x 64 lanes x 2 dw (A-frag, layer2^T 16x16x16)
//   [9216..9727]   PPTF: 2 tiles x 64 x 4 dw
//   [9728..10239]  MPTF: 2 tiles x 64 x 4 dw
//   [12288 ...]    zc: A1[nch][81920], A2[nch][81920], S[nch][81920]

// ================= k0: setup =================
__global__ __launch_bounds__(256) void k0_setup(
    const float* __restrict__ ts, const float* __restrict__ sigma,
    const float* __restrict__ A, const float* __restrict__ P,
    const float* __restrict__ Q, const float* __restrict__ W2,
    const float* __restrict__ b2, const float* __restrict__ W1,
    const float* __restrict__ b1, float* __restrict__ wsc) {
  __shared__ float aug[20][40];
  __shared__ float sS[400], sA[400], sT1[400];
  __shared__ float fac[20];
  int tid = threadIdx.x;
  for (int e = tid; e < 400; e += 256) { sS[e] = sigma[e]; sA[e] = A[e]; }
  for (int e = tid; e < 800; e += 256) {
    int i = e / 40, j = e % 40;
    aug[i][j] = (j < 20) ? sigma[i * 20 + j] : ((j - 20) == i ? 1.f : 0.f);
  }
  __syncthreads();
  for (int p = 0; p < 20; ++p) {
    if (tid < 64) {
      float pv = aug[p][p];
      float r = 1.f / pv;
      float rowv = 0.f, facv = 0.f;
      if (tid < 40) rowv = aug[p][tid];
      if (tid >= 40 && tid < 60) facv = aug[tid - 40][p];
      if (tid < 40) aug[p][tid] = rowv * r;
      if (tid >= 40 && tid < 60) fac[tid - 40] = facv;
    }
    __syncthreads();
    for (int e = tid; e < 800; e += 256) {
      int i = e / 40, j = e % 40;
      if (i != p) aug[i][j] -= fac[i] * aug[p][j];
    }
    __syncthreads();
  }
  // T1[k][j] = (A sigma^{-T})[k][j]
  for (int e = tid; e < 400; e += 256) {
    int k = e / 20, j = e % 20;
    float s = 0.f;
    for (int l2 = 0; l2 < 20; ++l2) s += sA[k * 20 + l2] * aug[j][20 + l2];
    sT1[e] = s;
  }
  __syncthreads();
  for (int e = tid; e < 400; e += 256) {
    int i = e / 20, j = e % 20;
    float m = 0.f, pp = 0.f, qq = 0.f;
    for (int k = 0; k < 20; ++k) {
      float sk = sS[k * 20 + i];
      m += sk * sT1[k * 20 + j];
      pp += sk * P[k * 20 + j];
      qq += sk * Q[k * 20 + j];
    }
    wsc[e] = pp;
    wsc[400 + e] = -m;
    wsc[800 + e] = qq;
  }
  for (int e = tid; e < 2560; e += 256) {
    int h = e / 20, i = e % 20;
    float s = 0.f;
    for (int j = 0; j < 20; ++j) s += W2[h * 20 + j] * sS[j * 20 + i];
    wsc[2048 + e] = s;
  }
  if (tid < 32) {
    float s = 0.f;
    if (tid < 20)
      for (int j = 0; j < 20; ++j) s += b2[j] * sS[j * 20 + tid];
    wsc[1600 + tid] = s;
  }
  if (tid < NSTEP) {
    float d = ts[tid + 1] - ts[tid];
    wsc[1200 + tid] = d;
    wsc[1400 + tid] = rsqrtf(d);
  }
  __syncthreads();

  unsigned* wu = (unsigned*)wsc;
  // W1TF (layer1^T A-frag): lane(quad,m16), n = nt*16+m16, k = quad*8+j
  for (int e = tid; e < 2048; e += 256) {
    int nt = e >> 8, rem = e & 255, l = rem >> 2, jj = rem & 3;
    int quad = l >> 4, m16 = l & 15;
    int n = nt * 16 + m16;
    int k0 = quad * 8 + 2 * jj;
    auto wf = [&](int k) -> float {
      if (k < 20) return W1[(k + 1) * HID + n];
      if (k == 20) return W1[n];       // t row
      if (k == 21) return b1[n];       // bias column (X supplies 1.0)
      return 0.f;
    };
    wu[5120 + e] = pk2(wf(k0), wf(k0 + 1));
  }
  // W2PTF (layer2^T 16x16x16 A-frags): frag f = hk*2+tile; 2 dw/lane
  for (int e = tid; e < 2048; e += 256) {
    int f = e >> 7, rem = e & 127, l = rem >> 1, jj = rem & 1;
    int hk = f >> 1, tile = f & 1;
    int m16 = l & 15;
    int quad = l >> 4;
    int d = tile ? 16 + m16 : m16;
    bool ok = (d < 20);
    int h0 = hk * 16 + quad * 4 + 2 * jj;
    float f0 = ok ? wsc[2048 + h0 * 20 + d] : 0.f;
    float f1 = ok ? wsc[2048 + (h0 + 1) * 20 + d] : 0.f;
    wu[7168 + e] = pk2(f0, f1);
  }
  // PPTF / MPTF (integrand^T A-frags, K=32 layout): tile in {0,1}
  for (int e = tid; e < 512; e += 256) {
    int tile = e >> 8, rem = e & 255, l = rem >> 2, jj = rem & 3;
    int quad = l >> 4, m16 = l & 15;
    int d = tile ? 16 + m16 : m16;
    bool ok = (d < 20);
    int k0 = quad * 8 + 2 * jj;
    float f0 = (ok && k0 < 20) ? wsc[d * 20 + k0] : 0.f;
    float f1 = (ok && k0 + 1 < 20) ? wsc[d * 20 + k0 + 1] : 0.f;
    wu[9216 + e] = pk2(f0, f1);
    float g0 = (ok && k0 < 20) ? wsc[400 + d * 20 + k0] : 0.f;
    float g1 = (ok && k0 + 1 < 20) ? wsc[400 + d * 20 + k0 + 1] : 0.f;
    wu[9728 + e] = pk2(g0, g1);
  }
}

// ================= kernel A: fully-transposed MLP scan, ZERO LDS =================
// r12 verified (absmax 0). ROUNDS MODEL (r7-r12): kA time = steps/chunk x
// ceil(blocks_per_CU / resident) x step_time; resident = 2 at this reg count.
// nch=12 gave 16.75 x 2 rounds = 33.5 serial step-times; nch=8 gives
// 25.1 x 1 round = 25.1 -> the 33% scheduling artifact this round removes.
// Scalar chain (ts/dt/rsd) now prefetched one iteration ahead like x/n/c.
// Canaries: FETCH >> 100 MB or WRITE >> 20 MB = spill; LDS_Block_Size must be 0.
__global__ __launch_bounds__(256, 2) void kA(
    const float* __restrict__ states, const float* __restrict__ noises,
    const float* __restrict__ controls, const float* __restrict__ ts,
    const float* __restrict__ wsc, float* __restrict__ zc,
    int nch, int cbase, int crem) {
  const int tid = threadIdx.x;
  const int l = tid & 63;
  const int w = tid >> 6;
  const int quad = l >> 4;
  const int m16 = l & 15;

  const int c = blockIdx.x >> 6;
  const int slab = blockIdx.x & 63;
  const int b0 = slab * 64 + w * 16;
  const int sz = cbase + ((c < crem) ? 1 : 0);
  const int thi = 200 - (c * cbase + ((c < crem) ? c : crem));
  const int tlo = thi - (sz - 1);

  // ---- weight fragments (coalesced loads from prepacked tables) ----
  short8 W1T[8];
#pragma unroll
  for (int nt = 0; nt < 8; ++nt)
    W1T[nt] = *(const short8*)(wsc + 5120 + nt * 256 + l * 4);
  sv4 W2T[16];
#pragma unroll
  for (int f = 0; f < 16; ++f)
    W2T[f] = *(const sv4*)(wsc + 7168 + f * 128 + l * 2);
  const short8 PPT0 = *(const short8*)(wsc + 9216 + l * 4);
  const short8 PPT1 = *(const short8*)(wsc + 9472 + l * 4);
  const short8 MPT0 = *(const short8*)(wsc + 9728 + l * 4);
  const short8 MPT1 = *(const short8*)(wsc + 9984 + l * 4);
  const f32x4 b2Av = *(const f32x4*)(wsc + 1600 + quad * 4);
  const f32x4 b2Bv = *(const f32x4*)(wsc + 1616 + quad * 4);

  // ---- global pointers (16B-aligned per-quad slices) ----
  const int row20 = (b0 + m16) * 20;
  const int qoff = (quad == 0) ? 0 : ((quad == 1) ? 8 : 12);
  const float* gx = states + row20 + qoff;
  const float* gn = noises + row20 + qoff;
  const float* gc = controls + row20 + qoff;

  // ---- scan accumulators (tile0: d=quad*4+reg; tile1: d=16+reg, quad0 only) ----
  f32x4 A1a = {0.f, 0.f, 0.f, 0.f}, A1b = {0.f, 0.f, 0.f, 0.f};
  f32x4 A2a = {0.f, 0.f, 0.f, 0.f}, A2b = {0.f, 0.f, 0.f, 0.f};
  f32x4 La = {0.f, 0.f, 0.f, 0.f}, Lb = {0.f, 0.f, 0.f, 0.f};

  // ---- preload first t (vector + scalar) ----
  float4 xv0, xv1, nv0 = {0, 0, 0, 0}, nv1 = {0, 0, 0, 0};
  float4 cv0 = {0, 0, 0, 0}, cv1 = {0, 0, 0, 0};
  float tval, dtv = 0.f, rsd = 0.f;
  {
    size_t rb = (size_t)thi * (BATCH * 20);
    xv0 = *(const float4*)(gx + rb);
    xv1 = *(const float4*)(gx + rb + 4);
    tval = ts[thi];
    if (thi < 200) {
      nv0 = *(const float4*)(gn + rb); nv1 = *(const float4*)(gn + rb + 4);
      cv0 = *(const float4*)(gc + rb); cv1 = *(const float4*)(gc + rb + 4);
      dtv = wsc[1200 + thi]; rsd = wsc[1400 + thi];
    }
  }

#pragma unroll 1
  for (int t = thi; t >= tlo; --t) {
    float4 xn0, xn1, nn0, nn1, cn0, cn1;
    float tvn, dtn, rsn;
    if (t > tlo) {
      size_t rb = (size_t)(t - 1) * (BATCH * 20);
      xn0 = *(const float4*)(gx + rb); xn1 = *(const float4*)(gx + rb + 4);
      nn0 = *(const float4*)(gn + rb); nn1 = *(const float4*)(gn + rb + 4);
      cn0 = *(const float4*)(gc + rb); cn1 = *(const float4*)(gc + rb + 4);
      tvn = ts[t - 1];
      dtn = wsc[1200 + t - 1]; rsn = wsc[1400 + t - 1];
    }
    const bool has_s = (t < 200);

    // ---- X^T B-fragment (K order: x0..x19, t@20, 1.0@21) ----
    S8U af;
    if (quad <= 1) {
      af.u[0] = pk2(xv0.x, xv0.y); af.u[1] = pk2(xv0.z, xv0.w);
      af.u[2] = pk2(xv1.x, xv1.y); af.u[3] = pk2(xv1.z, xv1.w);
    } else if (quad == 2) {        // loads were x[12..19]
      af.u[0] = pk2(xv1.x, xv1.y); af.u[1] = pk2(xv1.z, xv1.w);
      af.u[2] = pk2(tval, 1.0f);   af.u[3] = 0u;
    } else {
      af.u[0] = af.u[1] = af.u[2] = af.u[3] = 0u;
    }
    const short8 afs = af.s;

    const f32x4 z4 = {0.f, 0.f, 0.f, 0.f};
    // ---- layer1^T: 8 independent MFMAs -> lane holds H^T[16nt+quad*4+reg][m16]
    f32x4 h0 = MFMA32(W1T[0], afs, z4);
    f32x4 h1 = MFMA32(W1T[1], afs, z4);
    f32x4 h2 = MFMA32(W1T[2], afs, z4);
    f32x4 h3 = MFMA32(W1T[3], afs, z4);
    f32x4 h4 = MFMA32(W1T[4], afs, z4);
    f32x4 h5 = MFMA32(W1T[5], afs, z4);
    f32x4 h6 = MFMA32(W1T[6], afs, z4);
    f32x4 h7 = MFMA32(W1T[7], afs, z4);

    // ---- layer2^T: tanh in regs -> 16x16x16 MFMAs, no lane permutation ----
    f32x4 u0 = b2Av, u1 = b2Bv;
#define L2STEP(hk, hr)                                                  \
    {                                                                   \
      S4U hb;                                                           \
      hb.u[0] = pk2(tanh_fast(hr[0]), tanh_fast(hr[1]));                \
      hb.u[1] = pk2(tanh_fast(hr[2]), tanh_fast(hr[3]));                \
      u0 = MFMA16K(W2T[2 * hk], hb.s, u0);                              \
      u1 = MFMA16K(W2T[2 * hk + 1], hb.s, u1);                          \
    }
    L2STEP(0, h0) L2STEP(1, h1) L2STEP(2, h2) L2STEP(3, h3)
    L2STEP(4, h4) L2STEP(5, h5) L2STEP(6, h6) L2STEP(7, h7)
#undef L2STEP

    // ---- integrand^T: S^T = Pp.X^T + Mp.Y^T (X frag reused) ----
    f32x4 s0 = z4, s1 = z4;
    if (has_s) {
      S8U yf;
      if (quad <= 1) {
        yf.u[0] = pk2(fmaf(nv0.x, rsd, cv0.x), fmaf(nv0.y, rsd, cv0.y));
        yf.u[1] = pk2(fmaf(nv0.z, rsd, cv0.z), fmaf(nv0.w, rsd, cv0.w));
        yf.u[2] = pk2(fmaf(nv1.x, rsd, cv1.x), fmaf(nv1.y, rsd, cv1.y));
        yf.u[3] = pk2(fmaf(nv1.z, rsd, cv1.z), fmaf(nv1.w, rsd, cv1.w));
      } else if (quad == 2) {
        yf.u[0] = pk2(fmaf(nv1.x, rsd, cv1.x), fmaf(nv1.y, rsd, cv1.y));
        yf.u[1] = pk2(fmaf(nv1.z, rsd, cv1.z), fmaf(nv1.w, rsd, cv1.w));
        yf.u[2] = 0u; yf.u[3] = 0u;
      } else {
        yf.u[0] = yf.u[1] = yf.u[2] = yf.u[3] = 0u;
      }
      f32x4 a0 = MFMA32(PPT0, afs, z4);
      a0 = MFMA32(MPT0, yf.s, a0);
      f32x4 a1 = MFMA32(PPT1, afs, z4);
      a1 = MFMA32(MPT1, yf.s, a1);
      s0 = a0 * dtv;
      s1 = a1 * dtv;
    }

    // ---- scan update ----
    La += s0;
    Lb += s1;
    f32x4 p0 = u0 - La;
    f32x4 p1 = u1 - Lb;
    A2a += p0;
    A2b += p1;
    A1a += p0 * p0;
    A1b += p1 * p1;

    // rotate prefetch (vector + scalar)
    xv0 = xn0; xv1 = xn1;
    nv0 = nn0; nv1 = nn1;
    cv0 = cn0; cv1 = cn1;
    tval = tvn; dtv = dtn; rsd = rsn;
  }

  // ---- epilogue: lane owns batch b0+m16, dims quad*4+reg (+16.. for quad0) ----
  const size_t CH = (size_t)BATCH * DIM;
  float* zA1 = zc;
  float* zA2 = zc + (size_t)nch * CH;
  float* zS = zc + (size_t)2 * nch * CH;
  size_t base = ((size_t)c * BATCH + (b0 + m16)) * 20 + quad * 4;
#pragma unroll
  for (int reg = 0; reg < 4; ++reg) {
    zA1[base + reg] = A1a[reg];
    zA2[base + reg] = A2a[reg];
    zS[base + reg] = La[reg];
  }
  if (quad == 0) {
#pragma unroll
    for (int reg = 0; reg < 4; ++reg) {
      zA1[base + 16 + reg] = A1b[reg];
      zA2[base + 16 + reg] = A2b[reg];
      zS[base + 16 + reg] = Lb[reg];
    }
  }
}

// ================= kernel B: combine chunks =================
__global__ __launch_bounds__(256) void kB(
    const float* __restrict__ states, const float* __restrict__ lw,
    const float* __restrict__ wsc, const float* __restrict__ zc,
    float* __restrict__ out, int nch, int cbase, int crem) {
  __shared__ float sQp[400];
  __shared__ float part[4];
  int tid = threadIdx.x;
  for (int e = tid; e < 400; e += 256) sQp[e] = wsc[800 + e];
  __syncthreads();
  const int u = blockIdx.x * 256 + tid;
  const int b = u / 20;
  const int i = u - b * 20;
  const float* xp = states + ((size_t)NSTEP * BATCH + b) * 20;
  float term = 0.f;
#pragma unroll
  for (int j = 0; j < 20; ++j) term = fmaf(sQp[i * 20 + j], xp[j], term);

  const size_t CH = (size_t)BATCH * DIM;
  float T = 0.f, obj = 0.f;
  for (int c = 0; c < nch; ++c) {
    float A1 = zc[(size_t)c * CH + u];
    float A2 = zc[(size_t)(nch + c) * CH + u];
    float S = zc[(size_t)(2 * nch + c) * CH + u];
    float K = term + T;
    float nc = (float)(cbase + ((c < crem) ? 1 : 0));
    obj += A1 - 2.f * K * A2 + nc * K * K;
    T += S;
  }
  obj *= __expf(lw[b]) * (1.f / ((float)TN * (float)BATCH));
#pragma unroll
  for (int off = 32; off > 0; off >>= 1) obj += __shfl_down(obj, off, 64);
  if ((tid & 63) == 0) part[tid >> 6] = obj;
  __syncthreads();
  if (tid == 0) atomicAdd(out, (part[0] + part[1]) + (part[2] + part[3]));
}

extern "C" void kernel_launch(void* const* d_in, const int* in_sizes, int n_in,
                              void* d_out, int out_size, void* d_ws, size_t ws_size,
                              hipStream_t stream) {
  const float* states = (const float*)d_in[0];
  const float* noises = (const float*)d_in[1];
  const float* controls = (const float*)d_in[2];
  const float* lw = (const float*)d_in[3];
  const float* ts = (const float*)d_in[4];
  const float* sigma = (const float*)d_in[5];
  const float* P = (const float*)d_in[6];
  const float* A = (const float*)d_in[7];
  const float* Q = (const float*)d_in[8];
  const float* W1 = (const float*)d_in[9];
  const float* b1 = (const float*)d_in[10];
  const float* W2 = (const float*)d_in[11];
  const float* b2 = (const float*)d_in[12];
  float* out = (float*)d_out;

  float* wsc = (float*)d_ws;
  float* zc = wsc + 12288;

  // nch=8 -> 512 blocks = exactly 2 blocks/CU = the resident count at this
  // reg budget -> ONE serial round of ~25 steps (nch=12 was 2 rounds of 17:
  // a 33% scheduling artifact). ws need: 12288 + 3*8*81920 floats = 7.9 MB.
  int nch = 8;
  size_t need = ((size_t)12288 + (size_t)3 * nch * BATCH * DIM) * sizeof(float);
  if (ws_size < need) nch = 4;
  int cbase = TN / nch;
  int crem = TN - cbase * nch;

  (void)hipMemsetAsync(out, 0, sizeof(float), stream);
  hipLaunchKernelGGL(k0_setup, dim3(1), dim3(256), 0, stream,
                     ts, sigma, A, P, Q, W2, b2, W1, b1, wsc);
  hipLaunchKernelGGL(kA, dim3(nch * 64), dim3(256), 0, stream,
                     states, noises, controls, ts, wsc, zc, nch, cbase, crem);
  hipLaunchKernelGGL(kB, dim3((BATCH * DIM) / 256), dim3(256), 0, stream,
                     states, lw, wsc, zc, out, nch, cbase, crem);
}